// Round 1
// baseline (1463.348 us; speedup 1.0000x reference)
//
#include <hip/hip_runtime.h>
#include <hip/hip_bf16.h>
#include <math.h>

#define HIDDEN 7168
#define NH 32
#define DQ 1536
#define DKV 512
#define DH 128
#define DR 64
#define SEQ 2048
#define DKVP 640   // DKV+DR=576 padded to multiple of 128

typedef unsigned short u16;
typedef __bf16 bf16_t;
typedef bf16_t bf16x8 __attribute__((ext_vector_type(8)));
typedef float f32x4 __attribute__((ext_vector_type(4)));

__device__ __forceinline__ float bf2f(u16 h) {
    union { unsigned u; float f; } q; q.u = ((unsigned)h) << 16; return q.f;
}
__device__ __forceinline__ u16 f2bf(float x) {
    union { float f; unsigned u; } q; q.f = x;
    unsigned r = q.u + 0x7fffu + ((q.u >> 16) & 1u);   // round-to-nearest-even
    return (u16)(r >> 16);
}

// ---------------------------------------------------------------------------
// C[M,N](f32 or bf16) = A[M,K](bf16 row-major, lda) @ B^T  where BT[N,K] (ldb)
// m97 structure: 128x128 tile, BK=32, 256 thr = 4 waves, each wave 64x64 via
// 4x4 grid of mfma_f32_16x16x32_bf16. global_load_lds width-16 staging.
// Batched over blockIdx.z with element strides sA,sB,sC.
// Requires: M%128==0, N%128==0, K%32==0, 16B-aligned rows.
// ---------------------------------------------------------------------------
template <typename CT>
__global__ __launch_bounds__(256) void gemm_bt(
    const u16* __restrict__ A, const u16* __restrict__ B, CT* __restrict__ C,
    int K, int lda, int ldb, int ldc, long sA, long sB, long sC)
{
    __shared__ u16 As[128 * 32];
    __shared__ u16 Bs[128 * 32];
    A += (long)blockIdx.z * sA;
    B += (long)blockIdx.z * sB;
    C += (long)blockIdx.z * sC;

    const int t = threadIdx.x;
    const int w = t >> 6, lane = t & 63;
    const int lane15 = lane & 15, quad = lane >> 4;
    const int brow = blockIdx.y * 128, bcol = blockIdx.x * 128;
    const int wrow = (w >> 1) * 64, wcol = (w & 1) * 64;

    f32x4 acc[4][4] = {};

    for (int k0 = 0; k0 < K; k0 += 32) {
#pragma unroll
        for (int i = 0; i < 2; ++i) {
            int chunk = i * 256 + t;          // 512 chunks of 8 bf16 (16B) per tile
            int row = chunk >> 2;
            int kc = (chunk & 3) * 8;
            const u16* ga = A + (long)(brow + row) * lda + k0 + kc;
            const u16* gb = B + (long)(bcol + row) * ldb + k0 + kc;
            // wave-uniform LDS base; HW scatters lane*16B
            u16* la = As + (i * 256 + w * 64) * 8;
            u16* lb = Bs + (i * 256 + w * 64) * 8;
            __builtin_amdgcn_global_load_lds(
                (const __attribute__((address_space(1))) void*)ga,
                (__attribute__((address_space(3))) void*)la, 16, 0, 0);
            __builtin_amdgcn_global_load_lds(
                (const __attribute__((address_space(1))) void*)gb,
                (__attribute__((address_space(3))) void*)lb, 16, 0, 0);
        }
        __syncthreads();   // drains vmcnt before barrier (compiler-inserted)

        bf16x8 af[4], bfr[4];
#pragma unroll
        for (int mi = 0; mi < 4; ++mi)
            af[mi] = *(const bf16x8*)(As + (wrow + mi * 16 + lane15) * 32 + quad * 8);
#pragma unroll
        for (int ni = 0; ni < 4; ++ni)
            bfr[ni] = *(const bf16x8*)(Bs + (wcol + ni * 16 + lane15) * 32 + quad * 8);
#pragma unroll
        for (int mi = 0; mi < 4; ++mi)
#pragma unroll
            for (int ni = 0; ni < 4; ++ni)
                acc[mi][ni] = __builtin_amdgcn_mfma_f32_16x16x32_bf16(
                    af[mi], bfr[ni], acc[mi][ni], 0, 0, 0);
        __syncthreads();
    }

    // C/D layout: col = lane&15, row = quad*4 + reg   [verified m89/m91]
#pragma unroll
    for (int mi = 0; mi < 4; ++mi) {
#pragma unroll
        for (int ni = 0; ni < 4; ++ni) {
            int r0 = brow + wrow + mi * 16 + quad * 4;
            int cc = bcol + wcol + ni * 16 + lane15;
#pragma unroll
            for (int r = 0; r < 4; ++r) {
                float v = acc[mi][ni][r];
                if constexpr (sizeof(CT) == 2) C[(long)(r0 + r) * ldc + cc] = f2bf(v);
                else                           C[(long)(r0 + r) * ldc + cc] = v;
            }
        }
    }
}

// ---------------------------------------------------------------------------
// fp32 -> bf16 elementwise cast (n % 4 == 0)
// ---------------------------------------------------------------------------
__global__ void cast_bf16_k(const float* __restrict__ in, u16* __restrict__ out, long n)
{
    long i = ((long)blockIdx.x * 256 + threadIdx.x) * 4;
    if (i >= n) return;
    float4 v = *(const float4*)(in + i);
    ushort4 o;
    o.x = f2bf(v.x); o.y = f2bf(v.y); o.z = f2bf(v.z); o.w = f2bf(v.w);
    *(ushort4*)(out + i) = o;
}

// ---------------------------------------------------------------------------
// in fp32 [K][N] -> out bf16 [Npad][K] (transpose + cast; pad rows zeroed)
// grid (Npad/32, K/32), block (32,8)
// ---------------------------------------------------------------------------
__global__ void transpose_cast(const float* __restrict__ in, u16* __restrict__ out,
                               int K, int N, int Npad)
{
    __shared__ float tile[32][33];
    int n0 = blockIdx.x * 32, k0 = blockIdx.y * 32;
    int tx = threadIdx.x, ty = threadIdx.y;
#pragma unroll
    for (int i = 0; i < 32; i += 8) {
        int k = k0 + ty + i, n = n0 + tx;
        tile[ty + i][tx] = (n < N) ? in[(long)k * N + n] : 0.f;
    }
    __syncthreads();
#pragma unroll
    for (int i = 0; i < 32; i += 8) {
        int n = n0 + ty + i, k = k0 + tx;
        out[(long)n * K + k] = f2bf(tile[tx][ty + i]);
    }
}

// ---------------------------------------------------------------------------
// RMSNorm over C cols (bf16 in, bf16 out, fp32 math). eps = finfo(f32).eps
// ---------------------------------------------------------------------------
__global__ __launch_bounds__(256) void rmsnorm_k(
    const u16* __restrict__ in, const float* __restrict__ g,
    u16* __restrict__ out, int C, int ldin)
{
    const int row = blockIdx.x;
    const u16* x = in + (long)row * ldin;
    float ss = 0.f;
    for (int c = threadIdx.x; c < C; c += 256) { float v = bf2f(x[c]); ss += v * v; }
#pragma unroll
    for (int off = 32; off; off >>= 1) ss += __shfl_down(ss, off, 64);
    __shared__ float red[4];
    if ((threadIdx.x & 63) == 0) red[threadIdx.x >> 6] = ss;
    __syncthreads();
    float tot = red[0] + red[1] + red[2] + red[3];
    float r = rsqrtf(tot / (float)C + 1.1920929e-07f);
    for (int c = threadIdx.x; c < C; c += 256)
        out[(long)row * C + c] = f2bf(bf2f(x[c]) * r * g[c]);
}

// ---------------------------------------------------------------------------
// RoPE helper: src points at the 64-dim rope block, i in [0,64)
// ---------------------------------------------------------------------------
__device__ __forceinline__ float rope_val(const u16* src, int i, int s)
{
    int j = i & 31;
    float invf = powf(10000.f, -(float)(2 * j) / 64.f);
    float fr = (float)s * invf;
    float sn, cs; sincosf(fr, &sn, &cs);
    float x = bf2f(src[i]);
    float xo = (i < 32) ? bf2f(src[i + 32]) : bf2f(src[i - 32]);
    return (i < 32) ? (x * cs - xo * sn) : (x * cs + xo * sn);
}

// q[NH][SEQ][192] from qcr[SEQ][NH*192] (rope on last 64). grid (SEQ,NH) block 192
__global__ void build_q_k(const u16* __restrict__ qcr, u16* __restrict__ q)
{
    int s = blockIdx.x, h = blockIdx.y, d = threadIdx.x;
    const u16* src = qcr + ((long)s * NH + h) * 192;
    float val = (d < 128) ? bf2f(src[d]) : rope_val(src + 128, d - 128, s);
    q[((long)h * SEQ + s) * 192 + d] = f2bf(val);
}

// k[NH][SEQ][192]: k_c from kv[SEQ][8192], k_r = rope(ckv[s][512..575]) shared
__global__ void build_k_k(const u16* __restrict__ kv, const u16* __restrict__ ckv,
                          u16* __restrict__ kbuf)
{
    int s = blockIdx.x, h = blockIdx.y, d = threadIdx.x;
    float val = (d < 128) ? bf2f(kv[(long)s * 8192 + h * 256 + d])
                          : rope_val(ckv + (long)s * DKVP + 512, d - 128, s);
    kbuf[((long)h * SEQ + s) * 192 + d] = f2bf(val);
}

// vT[NH][128][SEQ] from kv[SEQ][8192] (v = cols h*256+128 .. +255)
__global__ void build_vT_k(const u16* __restrict__ kv, u16* __restrict__ vT)
{
    __shared__ u16 tile[32][33];
    int s0 = blockIdx.x * 32, d0 = blockIdx.y * 32, h = blockIdx.z;
    int tx = threadIdx.x, ty = threadIdx.y;
#pragma unroll
    for (int i = 0; i < 32; i += 8)
        tile[ty + i][tx] = kv[(long)(s0 + ty + i) * 8192 + h * 256 + 128 + d0 + tx];
    __syncthreads();
#pragma unroll
    for (int i = 0; i < 32; i += 8)
        vT[((long)h * 128 + d0 + ty + i) * SEQ + s0 + tx] = tile[tx][ty + i];
}

// in-place softmax over rows of bf16 scores [HC][SEQ][SEQ]; grid (SEQ, HC)
__global__ __launch_bounds__(256) void softmax_k(u16* __restrict__ sc, float scale)
{
    long base = (long)blockIdx.y * SEQ * SEQ + (long)blockIdx.x * SEQ;
    u16* x = sc + base;
    float vals[8];
    float m = -1e30f;
#pragma unroll
    for (int i = 0; i < 8; ++i) {
        float v = bf2f(x[i * 256 + threadIdx.x]) * scale;
        vals[i] = v; m = fmaxf(m, v);
    }
#pragma unroll
    for (int off = 32; off; off >>= 1) m = fmaxf(m, __shfl_down(m, off, 64));
    __shared__ float red[4];
    if ((threadIdx.x & 63) == 0) red[threadIdx.x >> 6] = m;
    __syncthreads();
    m = fmaxf(fmaxf(red[0], red[1]), fmaxf(red[2], red[3]));
    float ssum = 0.f;
#pragma unroll
    for (int i = 0; i < 8; ++i) { vals[i] = __expf(vals[i] - m); ssum += vals[i]; }
#pragma unroll
    for (int off = 32; off; off >>= 1) ssum += __shfl_down(ssum, off, 64);
    __syncthreads();
    if ((threadIdx.x & 63) == 0) red[threadIdx.x >> 6] = ssum;
    __syncthreads();
    float inv = 1.f / (red[0] + red[1] + red[2] + red[3]);
#pragma unroll
    for (int i = 0; i < 8; ++i)
        x[i * 256 + threadIdx.x] = f2bf(vals[i] * inv);
}

// ---------------------------------------------------------------------------
extern "C" void kernel_launch(void* const* d_in, const int* in_sizes, int n_in,
                              void* d_out, int out_size, void* d_ws, size_t ws_size,
                              hipStream_t stream)
{
    const float* hidden = (const float*)d_in[0];
    const float* W_dq   = (const float*)d_in[1];
    const float* g_q    = (const float*)d_in[2];
    const float* W_uq   = (const float*)d_in[3];
    const float* W_dkv  = (const float*)d_in[4];
    const float* g_kv   = (const float*)d_in[5];
    const float* W_ukv  = (const float*)d_in[6];
    const float* W_o    = (const float*)d_in[7];
    float* out = (float*)d_out;

    // bump allocator over d_ws (~374 MB total)
    char* p = (char*)d_ws;
    auto alloc = [&](size_t bytes) {
        char* r = p; p += (bytes + 255) & ~(size_t)255; return r;
    };
    u16* hbf   = (u16*)alloc((size_t)SEQ * HIDDEN * 2);   // hidden bf16
    u16* WTdq  = (u16*)alloc((size_t)DQ * HIDDEN * 2);    // [1536][7168]
    u16* WTuq  = (u16*)alloc((size_t)6144 * DQ * 2);      // [6144][1536]
    u16* WTdkv = (u16*)alloc((size_t)DKVP * HIDDEN * 2);  // [640][7168] pad-zeroed
    u16* WTukv = (u16*)alloc((size_t)8192 * DKV * 2);     // [8192][512]
    u16* WTo   = (u16*)alloc((size_t)HIDDEN * 4096 * 2);  // [7168][4096]
    u16* cq    = (u16*)alloc((size_t)SEQ * DQ * 2);
    u16* nq    = (u16*)alloc((size_t)SEQ * DQ * 2);
    u16* qcr   = (u16*)alloc((size_t)SEQ * 6144 * 2);
    u16* ckv   = (u16*)alloc((size_t)SEQ * DKVP * 2);
    u16* nkv   = (u16*)alloc((size_t)SEQ * DKV * 2);
    u16* kvb   = (u16*)alloc((size_t)SEQ * 8192 * 2);
    u16* qb    = (u16*)alloc((size_t)NH * SEQ * 192 * 2);
    u16* kb    = (u16*)alloc((size_t)NH * SEQ * 192 * 2);
    u16* vT    = (u16*)alloc((size_t)NH * 128 * SEQ * 2);
    u16* scb   = (u16*)alloc((size_t)8 * SEQ * SEQ * 2);  // 8-head score chunk
    u16* ob    = (u16*)alloc((size_t)SEQ * 4096 * 2);
    (void)ws_size; (void)in_sizes; (void)n_in; (void)out_size;

    // --- cast / transpose weights & activations to bf16 ---
    cast_bf16_k<<<((long)SEQ * HIDDEN) / 1024, 256, 0, stream>>>(hidden, hbf, (long)SEQ * HIDDEN);
    transpose_cast<<<dim3(DQ / 32, HIDDEN / 32), dim3(32, 8), 0, stream>>>(W_dq, WTdq, HIDDEN, DQ, DQ);
    transpose_cast<<<dim3(6144 / 32, DQ / 32), dim3(32, 8), 0, stream>>>(W_uq, WTuq, DQ, 6144, 6144);
    transpose_cast<<<dim3(DKVP / 32, HIDDEN / 32), dim3(32, 8), 0, stream>>>(W_dkv, WTdkv, HIDDEN, 576, DKVP);
    transpose_cast<<<dim3(8192 / 32, DKV / 32), dim3(32, 8), 0, stream>>>(W_ukv, WTukv, DKV, 8192, 8192);
    transpose_cast<<<dim3(HIDDEN / 32, 4096 / 32), dim3(32, 8), 0, stream>>>(W_o, WTo, 4096, HIDDEN, HIDDEN);

    // --- projections ---
    gemm_bt<u16><<<dim3(DQ / 128, SEQ / 128), 256, 0, stream>>>(
        hbf, WTdq, cq, HIDDEN, HIDDEN, HIDDEN, DQ, 0, 0, 0);
    rmsnorm_k<<<SEQ, 256, 0, stream>>>(cq, g_q, nq, DQ, DQ);
    gemm_bt<u16><<<dim3(6144 / 128, SEQ / 128), 256, 0, stream>>>(
        nq, WTuq, qcr, DQ, DQ, DQ, 6144, 0, 0, 0);
    gemm_bt<u16><<<dim3(DKVP / 128, SEQ / 128), 256, 0, stream>>>(
        hbf, WTdkv, ckv, HIDDEN, HIDDEN, HIDDEN, DKVP, 0, 0, 0);
    rmsnorm_k<<<SEQ, 256, 0, stream>>>(ckv, g_kv, nkv, DKV, DKVP);
    gemm_bt<u16><<<dim3(8192 / 128, SEQ / 128), 256, 0, stream>>>(
        nkv, WTukv, kvb, DKV, DKV, DKV, 8192, 0, 0, 0);

    // --- assemble q/k (rope) and vT ---
    build_q_k<<<dim3(SEQ, NH), 192, 0, stream>>>(qcr, qb);
    build_k_k<<<dim3(SEQ, NH), 192, 0, stream>>>(kvb, ckv, kb);
    build_vT_k<<<dim3(SEQ / 32, 4, NH), dim3(32, 8), 0, stream>>>(kvb, vT);

    // --- attention, 8 heads per chunk ---
    const float scale = 0.07216878364870322f;  // 1/sqrt(192)
    for (int h0 = 0; h0 < NH; h0 += 8) {
        gemm_bt<u16><<<dim3(16, 16, 8), 256, 0, stream>>>(
            qb + (long)h0 * SEQ * 192, kb + (long)h0 * SEQ * 192, scb,
            192, 192, 192, SEQ, (long)SEQ * 192, (long)SEQ * 192, (long)SEQ * SEQ);
        softmax_k<<<dim3(SEQ, 8), 256, 0, stream>>>(scb, scale);
        gemm_bt<u16><<<dim3(1, 16, 8), 256, 0, stream>>>(
            scb, vT + (long)h0 * 128 * SEQ, ob + h0 * 128,
            SEQ, SEQ, SEQ, 4096, (long)SEQ * SEQ, (long)128 * SEQ, 128L);
    }

    // --- output projection (fp32 out) ---
    gemm_bt<float><<<dim3(HIDDEN / 128, SEQ / 128), 256, 0, stream>>>(
        ob, WTo, out, 4096, 4096, 4096, HIDDEN, 0, 0, 0);
}

// Round 2
// 1226.332 us; speedup vs baseline: 1.1933x; 1.1933x over previous
//
#include <hip/hip_runtime.h>
#include <hip/hip_bf16.h>
#include <math.h>

#define HIDDEN 7168
#define NH 32
#define DQ 1536
#define DKV 512
#define DH 128
#define DR 64
#define SEQ 2048
#define DKVP 640        // DKV+DR=576 padded to multiple of 128
#define NQKV 2176       // DQ + DKVP (fused down-proj width), 17*128

typedef unsigned short u16;
typedef __bf16 bf16_t;
typedef bf16_t bf16x8 __attribute__((ext_vector_type(8)));
typedef float f32x4 __attribute__((ext_vector_type(4)));

__device__ __forceinline__ float bf2f(u16 h) {
    union { unsigned u; float f; } q; q.u = ((unsigned)h) << 16; return q.f;
}
__device__ __forceinline__ u16 f2bf(float x) {
    union { float f; unsigned u; } q; q.f = x;
    unsigned r = q.u + 0x7fffu + ((q.u >> 16) & 1u);   // round-to-nearest-even
    return (u16)(r >> 16);
}

// ---------------------------------------------------------------------------
// C[M,N](f32 or bf16) = A[M,K](bf16 row-major, lda) @ B^T  where BT[N,K] (ldb)
// m97 structure: 128x128 tile, BK=32, 256 thr = 4 waves, each wave 64x64 via
// 4x4 grid of mfma_f32_16x16x32_bf16. global_load_lds width-16 staging.
// Batched over blockIdx.z with element strides sA,sB,sC.
// Requires: M%128==0, N%128==0, K%32==0, 16B-aligned rows.
// ---------------------------------------------------------------------------
template <typename CT>
__global__ __launch_bounds__(256) void gemm_bt(
    const u16* __restrict__ A, const u16* __restrict__ B, CT* __restrict__ C,
    int K, int lda, int ldb, int ldc, long sA, long sB, long sC)
{
    __shared__ u16 As[128 * 32];
    __shared__ u16 Bs[128 * 32];
    A += (long)blockIdx.z * sA;
    B += (long)blockIdx.z * sB;
    C += (long)blockIdx.z * sC;

    const int t = threadIdx.x;
    const int w = t >> 6, lane = t & 63;
    const int lane15 = lane & 15, quad = lane >> 4;
    const int brow = blockIdx.y * 128, bcol = blockIdx.x * 128;
    const int wrow = (w >> 1) * 64, wcol = (w & 1) * 64;

    f32x4 acc[4][4] = {};

    for (int k0 = 0; k0 < K; k0 += 32) {
#pragma unroll
        for (int i = 0; i < 2; ++i) {
            int chunk = i * 256 + t;          // 512 chunks of 8 bf16 (16B) per tile
            int row = chunk >> 2;
            int kc = (chunk & 3) * 8;
            const u16* ga = A + (long)(brow + row) * lda + k0 + kc;
            const u16* gb = B + (long)(bcol + row) * ldb + k0 + kc;
            // wave-uniform LDS base; HW scatters lane*16B
            u16* la = As + (i * 256 + w * 64) * 8;
            u16* lb = Bs + (i * 256 + w * 64) * 8;
            __builtin_amdgcn_global_load_lds(
                (const __attribute__((address_space(1))) void*)ga,
                (__attribute__((address_space(3))) void*)la, 16, 0, 0);
            __builtin_amdgcn_global_load_lds(
                (const __attribute__((address_space(1))) void*)gb,
                (__attribute__((address_space(3))) void*)lb, 16, 0, 0);
        }
        __syncthreads();

        bf16x8 af[4], bfr[4];
#pragma unroll
        for (int mi = 0; mi < 4; ++mi)
            af[mi] = *(const bf16x8*)(As + (wrow + mi * 16 + lane15) * 32 + quad * 8);
#pragma unroll
        for (int ni = 0; ni < 4; ++ni)
            bfr[ni] = *(const bf16x8*)(Bs + (wcol + ni * 16 + lane15) * 32 + quad * 8);
#pragma unroll
        for (int mi = 0; mi < 4; ++mi)
#pragma unroll
            for (int ni = 0; ni < 4; ++ni)
                acc[mi][ni] = __builtin_amdgcn_mfma_f32_16x16x32_bf16(
                    af[mi], bfr[ni], acc[mi][ni], 0, 0, 0);
        __syncthreads();
    }

    // C/D layout: col = lane&15, row = quad*4 + reg   [verified m89/m91]
#pragma unroll
    for (int mi = 0; mi < 4; ++mi) {
#pragma unroll
        for (int ni = 0; ni < 4; ++ni) {
            int r0 = brow + wrow + mi * 16 + quad * 4;
            int cc = bcol + wcol + ni * 16 + lane15;
#pragma unroll
            for (int r = 0; r < 4; ++r) {
                float v = acc[mi][ni][r];
                if constexpr (sizeof(CT) == 2) C[(long)(r0 + r) * ldc + cc] = f2bf(v);
                else                           C[(long)(r0 + r) * ldc + cc] = v;
            }
        }
    }
}

// ---------------------------------------------------------------------------
// fp32 -> bf16 elementwise cast (n % 4 == 0)
// ---------------------------------------------------------------------------
__global__ void cast_bf16_k(const float* __restrict__ in, u16* __restrict__ out, long n)
{
    long i = ((long)blockIdx.x * 256 + threadIdx.x) * 4;
    if (i >= n) return;
    float4 v = *(const float4*)(in + i);
    ushort4 o;
    o.x = f2bf(v.x); o.y = f2bf(v.y); o.z = f2bf(v.z); o.w = f2bf(v.w);
    *(ushort4*)(out + i) = o;
}

// ---------------------------------------------------------------------------
// in fp32 [K][N] -> out bf16 [Npad][K] (transpose + cast; pad rows zeroed)
// grid (Npad/32, K/32), block (32,8)
// ---------------------------------------------------------------------------
__global__ void transpose_cast(const float* __restrict__ in, u16* __restrict__ out,
                               int K, int N, int Npad)
{
    __shared__ float tile[32][33];
    int n0 = blockIdx.x * 32, k0 = blockIdx.y * 32;
    int tx = threadIdx.x, ty = threadIdx.y;
#pragma unroll
    for (int i = 0; i < 32; i += 8) {
        int k = k0 + ty + i, n = n0 + tx;
        tile[ty + i][tx] = (n < N) ? in[(long)k * N + n] : 0.f;
    }
    __syncthreads();
#pragma unroll
    for (int i = 0; i < 32; i += 8) {
        int n = n0 + ty + i, k = k0 + tx;
        out[(long)n * K + k] = f2bf(tile[tx][ty + i]);
    }
}

// ---------------------------------------------------------------------------
// RMSNorm over C cols (bf16 in, bf16 out, fp32 math). out stride = C.
// ---------------------------------------------------------------------------
__global__ __launch_bounds__(256) void rmsnorm_k(
    const u16* __restrict__ in, const float* __restrict__ g,
    u16* __restrict__ out, int C, int ldin)
{
    const int row = blockIdx.x;
    const u16* x = in + (long)row * ldin;
    float ss = 0.f;
    for (int c = threadIdx.x; c < C; c += 256) { float v = bf2f(x[c]); ss += v * v; }
#pragma unroll
    for (int off = 32; off; off >>= 1) ss += __shfl_down(ss, off, 64);
    __shared__ float red[4];
    if ((threadIdx.x & 63) == 0) red[threadIdx.x >> 6] = ss;
    __syncthreads();
    float tot = red[0] + red[1] + red[2] + red[3];
    float r = rsqrtf(tot / (float)C + 1.1920929e-07f);
    for (int c = threadIdx.x; c < C; c += 256)
        out[(long)row * C + c] = f2bf(bf2f(x[c]) * r * g[c]);
}

// ---------------------------------------------------------------------------
// RoPE helper: src points at the 64-dim rope block, i in [0,64)
// ---------------------------------------------------------------------------
__device__ __forceinline__ float rope_val(const u16* src, int i, int s)
{
    int j = i & 31;
    float invf = powf(10000.f, -(float)(2 * j) / 64.f);
    float fr = (float)s * invf;
    float sn, cs; sincosf(fr, &sn, &cs);
    float x = bf2f(src[i]);
    float xo = (i < 32) ? bf2f(src[i + 32]) : bf2f(src[i - 32]);
    return (i < 32) ? (x * cs - xo * sn) : (x * cs + xo * sn);
}

// q[NH][SEQ][192] from qcr[SEQ][NH*192] (rope on last 64). grid (SEQ,NH) block 192
__global__ void build_q_k(const u16* __restrict__ qcr, u16* __restrict__ q)
{
    int s = blockIdx.x, h = blockIdx.y, d = threadIdx.x;
    const u16* src = qcr + ((long)s * NH + h) * 192;
    float val = (d < 128) ? bf2f(src[d]) : rope_val(src + 128, d - 128, s);
    q[((long)h * SEQ + s) * 192 + d] = f2bf(val);
}

// k[NH][SEQ][192]: k_c from kv[SEQ][8192], k_r = rope(ropebuf[s][0..63]) shared
__global__ void build_k_k(const u16* __restrict__ kv, const u16* __restrict__ ropebuf,
                          int ldrope, u16* __restrict__ kbuf)
{
    int s = blockIdx.x, h = blockIdx.y, d = threadIdx.x;
    float val = (d < 128) ? bf2f(kv[(long)s * 8192 + h * 256 + d])
                          : rope_val(ropebuf + (long)s * ldrope, d - 128, s);
    kbuf[((long)h * SEQ + s) * 192 + d] = f2bf(val);
}

// vT[NH][128][SEQ] from kv[SEQ][8192] (v = cols h*256+128 .. +255)
__global__ void build_vT_k(const u16* __restrict__ kv, u16* __restrict__ vT)
{
    __shared__ u16 tile[32][33];
    int s0 = blockIdx.x * 32, d0 = blockIdx.y * 32, h = blockIdx.z;
    int tx = threadIdx.x, ty = threadIdx.y;
#pragma unroll
    for (int i = 0; i < 32; i += 8)
        tile[ty + i][tx] = kv[(long)(s0 + ty + i) * 8192 + h * 256 + 128 + d0 + tx];
    __syncthreads();
#pragma unroll
    for (int i = 0; i < 32; i += 8)
        vT[((long)h * 128 + d0 + ty + i) * SEQ + s0 + tx] = tile[tx][ty + i];
}

// in-place softmax over rows of bf16 scores [HC][SEQ][SEQ]; grid (SEQ, HC)
__global__ __launch_bounds__(256) void softmax_k(u16* __restrict__ sc, float scale)
{
    long base = (long)blockIdx.y * SEQ * SEQ + (long)blockIdx.x * SEQ;
    u16* x = sc + base;
    float vals[8];
    float m = -1e30f;
#pragma unroll
    for (int i = 0; i < 8; ++i) {
        float v = bf2f(x[i * 256 + threadIdx.x]) * scale;
        vals[i] = v; m = fmaxf(m, v);
    }
#pragma unroll
    for (int off = 32; off; off >>= 1) m = fmaxf(m, __shfl_down(m, off, 64));
    __shared__ float red[4];
    if ((threadIdx.x & 63) == 0) red[threadIdx.x >> 6] = m;
    __syncthreads();
    m = fmaxf(fmaxf(red[0], red[1]), fmaxf(red[2], red[3]));
    float ssum = 0.f;
#pragma unroll
    for (int i = 0; i < 8; ++i) { vals[i] = __expf(vals[i] - m); ssum += vals[i]; }
#pragma unroll
    for (int off = 32; off; off >>= 1) ssum += __shfl_down(ssum, off, 64);
    __syncthreads();
    if ((threadIdx.x & 63) == 0) red[threadIdx.x >> 6] = ssum;
    __syncthreads();
    float inv = 1.f / (red[0] + red[1] + red[2] + red[3]);
#pragma unroll
    for (int i = 0; i < 8; ++i)
        x[i * 256 + threadIdx.x] = f2bf(vals[i] * inv);
}

// ---------------------------------------------------------------------------
extern "C" void kernel_launch(void* const* d_in, const int* in_sizes, int n_in,
                              void* d_out, int out_size, void* d_ws, size_t ws_size,
                              hipStream_t stream)
{
    const float* hidden = (const float*)d_in[0];
    const float* W_dq   = (const float*)d_in[1];
    const float* g_q    = (const float*)d_in[2];
    const float* W_uq   = (const float*)d_in[3];
    const float* W_dkv  = (const float*)d_in[4];
    const float* g_kv   = (const float*)d_in[5];
    const float* W_ukv  = (const float*)d_in[6];
    const float* W_o    = (const float*)d_in[7];
    float* out = (float*)d_out;

    // bump allocator over d_ws
    char* p = (char*)d_ws;
    auto alloc = [&](size_t bytes) {
        char* r = p; p += (bytes + 255) & ~(size_t)255; return r;
    };
    u16* hbf   = (u16*)alloc((size_t)SEQ * HIDDEN * 2);     // hidden bf16
    u16* WTqkv = (u16*)alloc((size_t)NQKV * HIDDEN * 2);    // rows 0..1535 Wdq^T, 1536..2175 Wdkv^T(pad)
    u16* WTuq  = (u16*)alloc((size_t)6144 * DQ * 2);        // [6144][1536]
    u16* WTukv = (u16*)alloc((size_t)8192 * DKV * 2);       // [8192][512]
    u16* WTo   = (u16*)alloc((size_t)HIDDEN * 4096 * 2);    // [7168][4096]
    u16* cqc   = (u16*)alloc((size_t)SEQ * NQKV * 2);       // fused c_q | ckv_kr
    u16* nq    = (u16*)alloc((size_t)SEQ * DQ * 2);
    u16* qcr   = (u16*)alloc((size_t)SEQ * 6144 * 2);
    u16* nkv   = (u16*)alloc((size_t)SEQ * DKV * 2);
    u16* kvb   = (u16*)alloc((size_t)SEQ * 8192 * 2);
    u16* qb    = (u16*)alloc((size_t)NH * SEQ * 192 * 2);
    u16* kb    = (u16*)alloc((size_t)NH * SEQ * 192 * 2);
    u16* vT    = (u16*)alloc((size_t)NH * 128 * SEQ * 2);
    u16* ob    = (u16*)alloc((size_t)SEQ * 4096 * 2);

    // adaptive head-chunking for the score buffer (268 MB at H=32);
    // H=8 reproduces round-1's proven 374 MB footprint.
    size_t base_used = (size_t)(p - (char*)d_ws);
    const size_t per_head = (size_t)SEQ * SEQ * 2;
    int H = 8;
    if (ws_size >= base_used + 32 * per_head)      H = 32;
    else if (ws_size >= base_used + 16 * per_head) H = 16;
    u16* scb = (u16*)alloc((size_t)H * per_head);
    (void)in_sizes; (void)n_in; (void)out_size;

    // --- cast / transpose weights & activations to bf16 ---
    cast_bf16_k<<<((long)SEQ * HIDDEN) / 1024, 256, 0, stream>>>(hidden, hbf, (long)SEQ * HIDDEN);
    transpose_cast<<<dim3(DQ / 32, HIDDEN / 32), dim3(32, 8), 0, stream>>>(W_dq, WTqkv, HIDDEN, DQ, DQ);
    transpose_cast<<<dim3(DKVP / 32, HIDDEN / 32), dim3(32, 8), 0, stream>>>(
        W_dkv, WTqkv + (size_t)DQ * HIDDEN, HIDDEN, 576, DKVP);
    transpose_cast<<<dim3(6144 / 32, DQ / 32), dim3(32, 8), 0, stream>>>(W_uq, WTuq, DQ, 6144, 6144);
    transpose_cast<<<dim3(8192 / 32, DKV / 32), dim3(32, 8), 0, stream>>>(W_ukv, WTukv, DKV, 8192, 8192);
    transpose_cast<<<dim3(HIDDEN / 32, 4096 / 32), dim3(32, 8), 0, stream>>>(W_o, WTo, 4096, HIDDEN, HIDDEN);

    // --- fused down-projection: cqc = hbf @ [W_dq | W_dkv]  (N=2176, 272 blocks) ---
    gemm_bt<u16><<<dim3(NQKV / 128, SEQ / 128), 256, 0, stream>>>(
        hbf, WTqkv, cqc, HIDDEN, HIDDEN, HIDDEN, NQKV, 0, 0, 0);
    rmsnorm_k<<<SEQ, 256, 0, stream>>>(cqc, g_q, nq, DQ, NQKV);
    rmsnorm_k<<<SEQ, 256, 0, stream>>>(cqc + DQ, g_kv, nkv, DKV, NQKV);

    // --- up-projections ---
    gemm_bt<u16><<<dim3(6144 / 128, SEQ / 128), 256, 0, stream>>>(
        nq, WTuq, qcr, DQ, DQ, DQ, 6144, 0, 0, 0);
    gemm_bt<u16><<<dim3(8192 / 128, SEQ / 128), 256, 0, stream>>>(
        nkv, WTukv, kvb, DKV, DKV, DKV, 8192, 0, 0, 0);

    // --- assemble q/k (rope) and vT; k_r source = cqc cols 2048..2111 ---
    build_q_k<<<dim3(SEQ, NH), 192, 0, stream>>>(qcr, qb);
    build_k_k<<<dim3(SEQ, NH), 192, 0, stream>>>(kvb, cqc + DQ + DKV, NQKV, kb);
    build_vT_k<<<dim3(SEQ / 32, 4, NH), dim3(32, 8), 0, stream>>>(kvb, vT);

    // --- attention, H heads per chunk ---
    const float scale = 0.07216878364870322f;  // 1/sqrt(192)
    for (int h0 = 0; h0 < NH; h0 += H) {
        gemm_bt<u16><<<dim3(16, 16, H), 256, 0, stream>>>(
            qb + (long)h0 * SEQ * 192, kb + (long)h0 * SEQ * 192, scb,
            192, 192, 192, SEQ, (long)SEQ * 192, (long)SEQ * 192, (long)SEQ * SEQ);
        softmax_k<<<dim3(SEQ, H), 256, 0, stream>>>(scb, scale);
        gemm_bt<u16><<<dim3(1, 16, H), 256, 0, stream>>>(
            scb, vT + (long)h0 * 128 * SEQ, ob + h0 * 128,
            SEQ, SEQ, SEQ, 4096, (long)SEQ * SEQ, (long)128 * SEQ, 128L);
    }

    // --- output projection (fp32 out) ---
    gemm_bt<float><<<dim3(HIDDEN / 128, SEQ / 128), 256, 0, stream>>>(
        ob, WTo, out, 4096, 4096, 4096, HIDDEN, 0, 0, 0);
}

// Round 3
// 1115.311 us; speedup vs baseline: 1.3121x; 1.0995x over previous
//
#include <hip/hip_runtime.h>
#include <hip/hip_bf16.h>
#include <math.h>

#define HIDDEN 7168
#define NH 32
#define DQ 1536
#define DKV 512
#define DH 128
#define DR 64
#define SEQ 2048
#define DKVP 640        // DKV+DR=576 padded to multiple of 128
#define NQKV 2176       // DQ + DKVP (fused down-proj width), 17*128

typedef unsigned short u16;
typedef __bf16 bf16_t;
typedef bf16_t bf16x8 __attribute__((ext_vector_type(8)));
typedef float f32x4 __attribute__((ext_vector_type(4)));

__device__ __forceinline__ float bf2f(u16 h) {
    union { unsigned u; float f; } q; q.u = ((unsigned)h) << 16; return q.f;
}
__device__ __forceinline__ u16 f2bf(float x) {
    union { float f; unsigned u; } q; q.f = x;
    unsigned r = q.u + 0x7fffu + ((q.u >> 16) & 1u);   // round-to-nearest-even
    return (u16)(r >> 16);
}

// ---------------------------------------------------------------------------
// C[M,N](f32 or bf16) = A[M,K](bf16 row-major, lda) @ B^T  where BT[N,K] (ldb)
// m97 structure. Batched over blockIdx.z with element strides sA,sB,sC.
// ---------------------------------------------------------------------------
template <typename CT>
__global__ __launch_bounds__(256) void gemm_bt(
    const u16* __restrict__ A, const u16* __restrict__ B, CT* __restrict__ C,
    int K, int lda, int ldb, int ldc, long sA, long sB, long sC)
{
    __shared__ u16 As[128 * 32];
    __shared__ u16 Bs[128 * 32];
    A += (long)blockIdx.z * sA;
    B += (long)blockIdx.z * sB;
    C += (long)blockIdx.z * sC;

    const int t = threadIdx.x;
    const int w = t >> 6, lane = t & 63;
    const int lane15 = lane & 15, quad = lane >> 4;
    const int brow = blockIdx.y * 128, bcol = blockIdx.x * 128;
    const int wrow = (w >> 1) * 64, wcol = (w & 1) * 64;

    f32x4 acc[4][4] = {};

    for (int k0 = 0; k0 < K; k0 += 32) {
#pragma unroll
        for (int i = 0; i < 2; ++i) {
            int chunk = i * 256 + t;
            int row = chunk >> 2;
            int kc = (chunk & 3) * 8;
            const u16* ga = A + (long)(brow + row) * lda + k0 + kc;
            const u16* gb = B + (long)(bcol + row) * ldb + k0 + kc;
            u16* la = As + (i * 256 + w * 64) * 8;
            u16* lb = Bs + (i * 256 + w * 64) * 8;
            __builtin_amdgcn_global_load_lds(
                (const __attribute__((address_space(1))) void*)ga,
                (__attribute__((address_space(3))) void*)la, 16, 0, 0);
            __builtin_amdgcn_global_load_lds(
                (const __attribute__((address_space(1))) void*)gb,
                (__attribute__((address_space(3))) void*)lb, 16, 0, 0);
        }
        __syncthreads();

        bf16x8 af[4], bfr[4];
#pragma unroll
        for (int mi = 0; mi < 4; ++mi)
            af[mi] = *(const bf16x8*)(As + (wrow + mi * 16 + lane15) * 32 + quad * 8);
#pragma unroll
        for (int ni = 0; ni < 4; ++ni)
            bfr[ni] = *(const bf16x8*)(Bs + (wcol + ni * 16 + lane15) * 32 + quad * 8);
#pragma unroll
        for (int mi = 0; mi < 4; ++mi)
#pragma unroll
            for (int ni = 0; ni < 4; ++ni)
                acc[mi][ni] = __builtin_amdgcn_mfma_f32_16x16x32_bf16(
                    af[mi], bfr[ni], acc[mi][ni], 0, 0, 0);
        __syncthreads();
    }

#pragma unroll
    for (int mi = 0; mi < 4; ++mi) {
#pragma unroll
        for (int ni = 0; ni < 4; ++ni) {
            int r0 = brow + wrow + mi * 16 + quad * 4;
            int cc = bcol + wcol + ni * 16 + lane15;
#pragma unroll
            for (int r = 0; r < 4; ++r) {
                float v = acc[mi][ni][r];
                if constexpr (sizeof(CT) == 2) C[(long)(r0 + r) * ldc + cc] = f2bf(v);
                else                           C[(long)(r0 + r) * ldc + cc] = v;
            }
        }
    }
}

// ---------------------------------------------------------------------------
// Fused flash attention.
// grid (SEQ/128, NH), 256 thr = 4 waves; wave w owns q rows [bq*128+w*32, +32).
// Q frags in registers; per 64-key tile: stage K(64x192)/VT(128x64) in padded
// LDS, QK^T MFMA -> online softmax in regs (quad-local shfl_xor row reduce) ->
// P via wave-private LDS (C-layout -> A-layout) -> PV MFMA into O regs.
// ---------------------------------------------------------------------------
__global__ __launch_bounds__(256, 2) void flash_attn(
    const u16* __restrict__ qb, const u16* __restrict__ kb,
    const u16* __restrict__ vT, u16* __restrict__ ob, float scale)
{
    __shared__ u16 Ks[64 * 196];      // pad 192->196: row stride 2 banks
    __shared__ u16 Vs[128 * 68];      // pad 64->68
    __shared__ u16 Ps[4 * 32 * 68];   // wave-private P tiles

    const int t = threadIdx.x;
    const int w = t >> 6, lane = t & 63;
    const int lane15 = lane & 15, quad = lane >> 4;
    const int h = blockIdx.y;
    const int q0 = blockIdx.x * 128 + w * 32;
    u16* Psw = Ps + w * 32 * 68;

    // Q fragments (A-layout): rows q0+mi*16+lane15, k = kc*32+quad*8
    bf16x8 Qf[2][6];
#pragma unroll
    for (int mi = 0; mi < 2; ++mi)
#pragma unroll
        for (int kc = 0; kc < 6; ++kc)
            Qf[mi][kc] = *(const bf16x8*)(
                qb + (long)(h * SEQ + q0 + mi * 16 + lane15) * 192 + kc * 32 + quad * 8);

    f32x4 O[2][8] = {};
    float mst[2][4], lst[2][4];
#pragma unroll
    for (int mi = 0; mi < 2; ++mi)
#pragma unroll
        for (int r = 0; r < 4; ++r) { mst[mi][r] = -3.0e38f; lst[mi][r] = 0.f; }

    for (int kt = 0; kt < SEQ / 64; ++kt) {
        // ---- stage K tile [64][192] and V^T tile [128][64] (VGPR roundtrip, padded) ----
#pragma unroll
        for (int i = 0; i < 6; ++i) {
            int chunk = i * 256 + t;          // 1536 chunks of 8
            int row = chunk / 24, c8 = (chunk % 24) * 8;
            bf16x8 v = *(const bf16x8*)(kb + (long)(h * SEQ + kt * 64 + row) * 192 + c8);
            *(bf16x8*)(Ks + row * 196 + c8) = v;
        }
#pragma unroll
        for (int i = 0; i < 4; ++i) {
            int chunk = i * 256 + t;          // 1024 chunks of 8
            int dh = chunk >> 3, c8 = (chunk & 7) * 8;
            bf16x8 v = *(const bf16x8*)(vT + (long)(h * 128 + dh) * SEQ + kt * 64 + c8);
            *(bf16x8*)(Vs + dh * 68 + c8) = v;
        }
        __syncthreads();

        // ---- S = Q @ K^T  (32 q x 64 keys per wave) ----
        f32x4 S[2][4] = {};
#pragma unroll
        for (int kc = 0; kc < 6; ++kc) {
            bf16x8 Kf[4];
#pragma unroll
            for (int ni = 0; ni < 4; ++ni)
                Kf[ni] = *(const bf16x8*)(Ks + (ni * 16 + lane15) * 196 + kc * 32 + quad * 8);
#pragma unroll
            for (int mi = 0; mi < 2; ++mi)
#pragma unroll
                for (int ni = 0; ni < 4; ++ni)
                    S[mi][ni] = __builtin_amdgcn_mfma_f32_16x16x32_bf16(
                        Qf[mi][kc], Kf[ni], S[mi][ni], 0, 0, 0);
        }

        // ---- online softmax (rows quad*4+r; row's 16 cols live in 16-lane group) ----
#pragma unroll
        for (int mi = 0; mi < 2; ++mi) {
#pragma unroll
            for (int r = 0; r < 4; ++r) {
                float rm = fmaxf(fmaxf(S[0][0][r], S[0][0][r]), S[mi][0][r]);
                rm = S[mi][0][r];
#pragma unroll
                for (int ni = 1; ni < 4; ++ni) rm = fmaxf(rm, S[mi][ni][r]);
#pragma unroll
                for (int m = 1; m < 16; m <<= 1) rm = fmaxf(rm, __shfl_xor(rm, m, 64));
                rm *= scale;
                float mnew = fmaxf(mst[mi][r], rm);
                float alpha = __expf(mst[mi][r] - mnew);
                mst[mi][r] = mnew;
                float rs = 0.f;
#pragma unroll
                for (int ni = 0; ni < 4; ++ni) {
                    float pv = __expf(S[mi][ni][r] * scale - mnew);
                    S[mi][ni][r] = pv; rs += pv;
                }
#pragma unroll
                for (int m = 1; m < 16; m <<= 1) rs += __shfl_xor(rs, m, 64);
                lst[mi][r] = lst[mi][r] * alpha + rs;
#pragma unroll
                for (int ni = 0; ni < 8; ++ni) O[mi][ni][r] *= alpha;
            }
        }

        // ---- P: C-layout regs -> wave-private LDS (A-layout readable) ----
#pragma unroll
        for (int mi = 0; mi < 2; ++mi)
#pragma unroll
            for (int ni = 0; ni < 4; ++ni)
#pragma unroll
                for (int r = 0; r < 4; ++r)
                    Psw[(mi * 16 + quad * 4 + r) * 68 + ni * 16 + lane15] =
                        f2bf(S[mi][ni][r]);

        // ---- O += P @ V ----
#pragma unroll
        for (int kc2 = 0; kc2 < 2; ++kc2) {
            bf16x8 Pf[2], Vf[8];
#pragma unroll
            for (int mi = 0; mi < 2; ++mi)
                Pf[mi] = *(const bf16x8*)(Psw + (mi * 16 + lane15) * 68 + kc2 * 32 + quad * 8);
#pragma unroll
            for (int ni = 0; ni < 8; ++ni)
                Vf[ni] = *(const bf16x8*)(Vs + (ni * 16 + lane15) * 68 + kc2 * 32 + quad * 8);
#pragma unroll
            for (int mi = 0; mi < 2; ++mi)
#pragma unroll
                for (int ni = 0; ni < 8; ++ni)
                    O[mi][ni] = __builtin_amdgcn_mfma_f32_16x16x32_bf16(
                        Pf[mi], Vf[ni], O[mi][ni], 0, 0, 0);
        }
        __syncthreads();
    }

    // ---- epilogue: normalize rows by 1/l, store ob[s][h*128+dh] ----
#pragma unroll
    for (int mi = 0; mi < 2; ++mi)
#pragma unroll
        for (int r = 0; r < 4; ++r) {
            float inv = 1.f / lst[mi][r];
            int row = q0 + mi * 16 + quad * 4 + r;
#pragma unroll
            for (int ni = 0; ni < 8; ++ni) {
                int col = h * 128 + ni * 16 + lane15;
                ob[(long)row * 4096 + col] = f2bf(O[mi][ni][r] * inv);
            }
        }
}

// ---------------------------------------------------------------------------
__global__ void cast_bf16_k(const float* __restrict__ in, u16* __restrict__ out, long n)
{
    long i = ((long)blockIdx.x * 256 + threadIdx.x) * 4;
    if (i >= n) return;
    float4 v = *(const float4*)(in + i);
    ushort4 o;
    o.x = f2bf(v.x); o.y = f2bf(v.y); o.z = f2bf(v.z); o.w = f2bf(v.w);
    *(ushort4*)(out + i) = o;
}

__global__ void transpose_cast(const float* __restrict__ in, u16* __restrict__ out,
                               int K, int N, int Npad)
{
    __shared__ float tile[32][33];
    int n0 = blockIdx.x * 32, k0 = blockIdx.y * 32;
    int tx = threadIdx.x, ty = threadIdx.y;
#pragma unroll
    for (int i = 0; i < 32; i += 8) {
        int k = k0 + ty + i, n = n0 + tx;
        tile[ty + i][tx] = (n < N) ? in[(long)k * N + n] : 0.f;
    }
    __syncthreads();
#pragma unroll
    for (int i = 0; i < 32; i += 8) {
        int n = n0 + ty + i, k = k0 + tx;
        out[(long)n * K + k] = f2bf(tile[tx][ty + i]);
    }
}

__global__ __launch_bounds__(256) void rmsnorm_k(
    const u16* __restrict__ in, const float* __restrict__ g,
    u16* __restrict__ out, int C, int ldin)
{
    const int row = blockIdx.x;
    const u16* x = in + (long)row * ldin;
    float ss = 0.f;
    for (int c = threadIdx.x; c < C; c += 256) { float v = bf2f(x[c]); ss += v * v; }
#pragma unroll
    for (int off = 32; off; off >>= 1) ss += __shfl_down(ss, off, 64);
    __shared__ float red[4];
    if ((threadIdx.x & 63) == 0) red[threadIdx.x >> 6] = ss;
    __syncthreads();
    float tot = red[0] + red[1] + red[2] + red[3];
    float r = rsqrtf(tot / (float)C + 1.1920929e-07f);
    for (int c = threadIdx.x; c < C; c += 256)
        out[(long)row * C + c] = f2bf(bf2f(x[c]) * r * g[c]);
}

// ---------------------------------------------------------------------------
// RoPE tables: ct/st[s][j] = cos/sin(s * 10000^(-2j/64)), j<32
// ---------------------------------------------------------------------------
__global__ void rope_tab_k(float* __restrict__ ct, float* __restrict__ st)
{
    int idx = blockIdx.x * 256 + threadIdx.x;   // SEQ*32 total
    int s = idx >> 5, j = idx & 31;
    float invf = powf(10000.f, -(float)(2 * j) / 64.f);
    float fr = (float)s * invf;
    float sn, cs; sincosf(fr, &sn, &cs);
    ct[idx] = cs; st[idx] = sn;
}

__device__ __forceinline__ float rope_val(const u16* src, int i, int s,
                                          const float* ct, const float* st)
{
    int j = i & 31;
    float cs = ct[s * 32 + j], sn = st[s * 32 + j];
    float x = bf2f(src[i]);
    float xo = (i < 32) ? bf2f(src[i + 32]) : bf2f(src[i - 32]);
    return (i < 32) ? (x * cs - xo * sn) : (x * cs + xo * sn);
}

// q[NH][SEQ][192] from qcr[SEQ][NH*192] (rope on last 64). grid (SEQ,NH) block 192
__global__ void build_q_k(const u16* __restrict__ qcr, u16* __restrict__ q,
                          const float* __restrict__ ct, const float* __restrict__ st)
{
    int s = blockIdx.x, h = blockIdx.y, d = threadIdx.x;
    const u16* src = qcr + ((long)s * NH + h) * 192;
    float val = (d < 128) ? bf2f(src[d]) : rope_val(src + 128, d - 128, s, ct, st);
    q[((long)h * SEQ + s) * 192 + d] = f2bf(val);
}

__global__ void build_k_k(const u16* __restrict__ kv, const u16* __restrict__ ropebuf,
                          int ldrope, u16* __restrict__ kbuf,
                          const float* __restrict__ ct, const float* __restrict__ st)
{
    int s = blockIdx.x, h = blockIdx.y, d = threadIdx.x;
    float val = (d < 128) ? bf2f(kv[(long)s * 8192 + h * 256 + d])
                          : rope_val(ropebuf + (long)s * ldrope, d - 128, s, ct, st);
    kbuf[((long)h * SEQ + s) * 192 + d] = f2bf(val);
}

// vT[NH][128][SEQ] from kv[SEQ][8192] (v = cols h*256+128 .. +255)
__global__ void build_vT_k(const u16* __restrict__ kv, u16* __restrict__ vT)
{
    __shared__ u16 tile[32][33];
    int s0 = blockIdx.x * 32, d0 = blockIdx.y * 32, h = blockIdx.z;
    int tx = threadIdx.x, ty = threadIdx.y;
#pragma unroll
    for (int i = 0; i < 32; i += 8)
        tile[ty + i][tx] = kv[(long)(s0 + ty + i) * 8192 + h * 256 + 128 + d0 + tx];
    __syncthreads();
#pragma unroll
    for (int i = 0; i < 32; i += 8)
        vT[((long)h * 128 + d0 + ty + i) * SEQ + s0 + tx] = tile[tx][ty + i];
}

// ---------------------------------------------------------------------------
extern "C" void kernel_launch(void* const* d_in, const int* in_sizes, int n_in,
                              void* d_out, int out_size, void* d_ws, size_t ws_size,
                              hipStream_t stream)
{
    const float* hidden = (const float*)d_in[0];
    const float* W_dq   = (const float*)d_in[1];
    const float* g_q    = (const float*)d_in[2];
    const float* W_uq   = (const float*)d_in[3];
    const float* W_dkv  = (const float*)d_in[4];
    const float* g_kv   = (const float*)d_in[5];
    const float* W_ukv  = (const float*)d_in[6];
    const float* W_o    = (const float*)d_in[7];
    float* out = (float*)d_out;

    char* p = (char*)d_ws;
    auto alloc = [&](size_t bytes) {
        char* r = p; p += (bytes + 255) & ~(size_t)255; return r;
    };
    u16* hbf   = (u16*)alloc((size_t)SEQ * HIDDEN * 2);
    u16* WTqkv = (u16*)alloc((size_t)NQKV * HIDDEN * 2);
    u16* WTuq  = (u16*)alloc((size_t)6144 * DQ * 2);
    u16* WTukv = (u16*)alloc((size_t)8192 * DKV * 2);
    u16* WTo   = (u16*)alloc((size_t)HIDDEN * 4096 * 2);
    u16* cqc   = (u16*)alloc((size_t)SEQ * NQKV * 2);
    u16* nq    = (u16*)alloc((size_t)SEQ * DQ * 2);
    u16* qcr   = (u16*)alloc((size_t)SEQ * 6144 * 2);
    u16* nkv   = (u16*)alloc((size_t)SEQ * DKV * 2);
    u16* kvb   = (u16*)alloc((size_t)SEQ * 8192 * 2);
    u16* qb    = (u16*)alloc((size_t)NH * SEQ * 192 * 2);
    u16* kb    = (u16*)alloc((size_t)NH * SEQ * 192 * 2);
    u16* vT    = (u16*)alloc((size_t)NH * 128 * SEQ * 2);
    u16* ob    = (u16*)alloc((size_t)SEQ * 4096 * 2);
    float* ct  = (float*)alloc((size_t)SEQ * 32 * 4);
    float* st  = (float*)alloc((size_t)SEQ * 32 * 4);
    (void)in_sizes; (void)n_in; (void)out_size; (void)ws_size;

    // --- prep: rope tables, casts, weight transposes ---
    rope_tab_k<<<(SEQ * 32) / 256, 256, 0, stream>>>(ct, st);
    cast_bf16_k<<<((long)SEQ * HIDDEN) / 1024, 256, 0, stream>>>(hidden, hbf, (long)SEQ * HIDDEN);
    transpose_cast<<<dim3(DQ / 32, HIDDEN / 32), dim3(32, 8), 0, stream>>>(W_dq, WTqkv, HIDDEN, DQ, DQ);
    transpose_cast<<<dim3(DKVP / 32, HIDDEN / 32), dim3(32, 8), 0, stream>>>(
        W_dkv, WTqkv + (size_t)DQ * HIDDEN, HIDDEN, 576, DKVP);
    transpose_cast<<<dim3(6144 / 32, DQ / 32), dim3(32, 8), 0, stream>>>(W_uq, WTuq, DQ, 6144, 6144);
    transpose_cast<<<dim3(8192 / 32, DKV / 32), dim3(32, 8), 0, stream>>>(W_ukv, WTukv, DKV, 8192, 8192);
    transpose_cast<<<dim3(HIDDEN / 32, 4096 / 32), dim3(32, 8), 0, stream>>>(W_o, WTo, 4096, HIDDEN, HIDDEN);

    // --- fused down-projection: cqc = hbf @ [W_dq | W_dkv] ---
    gemm_bt<u16><<<dim3(NQKV / 128, SEQ / 128), 256, 0, stream>>>(
        hbf, WTqkv, cqc, HIDDEN, HIDDEN, HIDDEN, NQKV, 0, 0, 0);
    rmsnorm_k<<<SEQ, 256, 0, stream>>>(cqc, g_q, nq, DQ, NQKV);
    rmsnorm_k<<<SEQ, 256, 0, stream>>>(cqc + DQ, g_kv, nkv, DKV, NQKV);

    // --- up-projections ---
    gemm_bt<u16><<<dim3(6144 / 128, SEQ / 128), 256, 0, stream>>>(
        nq, WTuq, qcr, DQ, DQ, DQ, 6144, 0, 0, 0);
    gemm_bt<u16><<<dim3(8192 / 128, SEQ / 128), 256, 0, stream>>>(
        nkv, WTukv, kvb, DKV, DKV, DKV, 8192, 0, 0, 0);

    // --- assemble q/k (rope) and vT ---
    build_q_k<<<dim3(SEQ, NH), 192, 0, stream>>>(qcr, qb, ct, st);
    build_k_k<<<dim3(SEQ, NH), 192, 0, stream>>>(kvb, cqc + DQ + DKV, NQKV, kb, ct, st);
    build_vT_k<<<dim3(SEQ / 32, 4, NH), dim3(32, 8), 0, stream>>>(kvb, vT);

    // --- fused flash attention ---
    const float scale = 0.07216878364870322f;  // 1/sqrt(192)
    flash_attn<<<dim3(SEQ / 128, NH), 256, 0, stream>>>(qb, kb, vT, ob, scale);

    // --- output projection (fp32 out) ---
    gemm_bt<float><<<dim3(HIDDEN / 128, SEQ / 128), 256, 0, stream>>>(
        ob, WTo, out, 4096, 4096, 4096, HIDDEN, 0, 0, 0);
}

// Round 4
// 990.629 us; speedup vs baseline: 1.4772x; 1.1259x over previous
//
#include <hip/hip_runtime.h>
#include <hip/hip_bf16.h>
#include <math.h>

#define HIDDEN 7168
#define NH 32
#define DQ 1536
#define DKV 512
#define DH 128
#define DR 64
#define SEQ 2048
#define DKVP 640        // DKV+DR=576 padded to multiple of 128
#define NQKV 2176       // DQ + DKVP (fused down-proj width), 17*128

typedef unsigned short u16;
typedef __bf16 bf16_t;
typedef bf16_t bf16x8 __attribute__((ext_vector_type(8)));
typedef float f32x4 __attribute__((ext_vector_type(4)));

__device__ __forceinline__ float bf2f(u16 h) {
    union { unsigned u; float f; } q; q.u = ((unsigned)h) << 16; return q.f;
}
__device__ __forceinline__ u16 f2bf(float x) {
    union { float f; unsigned u; } q; q.f = x;
    unsigned r = q.u + 0x7fffu + ((q.u >> 16) & 1u);   // round-to-nearest-even
    return (u16)(r >> 16);
}

// ---------------------------------------------------------------------------
// C[M,N](f32 or bf16) = A[M,K](bf16 row-major, lda) @ B^T  where BT[N,K] (ldb)
// m97 structure. Batched over blockIdx.z with element strides sA,sB,sC.
// ---------------------------------------------------------------------------
template <typename CT>
__global__ __launch_bounds__(256) void gemm_bt(
    const u16* __restrict__ A, const u16* __restrict__ B, CT* __restrict__ C,
    int K, int lda, int ldb, int ldc, long sA, long sB, long sC)
{
    __shared__ u16 As[128 * 32];
    __shared__ u16 Bs[128 * 32];
    A += (long)blockIdx.z * sA;
    B += (long)blockIdx.z * sB;
    C += (long)blockIdx.z * sC;

    const int t = threadIdx.x;
    const int w = t >> 6, lane = t & 63;
    const int lane15 = lane & 15, quad = lane >> 4;
    const int brow = blockIdx.y * 128, bcol = blockIdx.x * 128;
    const int wrow = (w >> 1) * 64, wcol = (w & 1) * 64;

    f32x4 acc[4][4] = {};

    for (int k0 = 0; k0 < K; k0 += 32) {
#pragma unroll
        for (int i = 0; i < 2; ++i) {
            int chunk = i * 256 + t;
            int row = chunk >> 2;
            int kc = (chunk & 3) * 8;
            const u16* ga = A + (long)(brow + row) * lda + k0 + kc;
            const u16* gb = B + (long)(bcol + row) * ldb + k0 + kc;
            u16* la = As + (i * 256 + w * 64) * 8;
            u16* lb = Bs + (i * 256 + w * 64) * 8;
            __builtin_amdgcn_global_load_lds(
                (const __attribute__((address_space(1))) void*)ga,
                (__attribute__((address_space(3))) void*)la, 16, 0, 0);
            __builtin_amdgcn_global_load_lds(
                (const __attribute__((address_space(1))) void*)gb,
                (__attribute__((address_space(3))) void*)lb, 16, 0, 0);
        }
        __syncthreads();

        bf16x8 af[4], bfr[4];
#pragma unroll
        for (int mi = 0; mi < 4; ++mi)
            af[mi] = *(const bf16x8*)(As + (wrow + mi * 16 + lane15) * 32 + quad * 8);
#pragma unroll
        for (int ni = 0; ni < 4; ++ni)
            bfr[ni] = *(const bf16x8*)(Bs + (wcol + ni * 16 + lane15) * 32 + quad * 8);
#pragma unroll
        for (int mi = 0; mi < 4; ++mi)
#pragma unroll
            for (int ni = 0; ni < 4; ++ni)
                acc[mi][ni] = __builtin_amdgcn_mfma_f32_16x16x32_bf16(
                    af[mi], bfr[ni], acc[mi][ni], 0, 0, 0);
        __syncthreads();
    }

#pragma unroll
    for (int mi = 0; mi < 4; ++mi) {
#pragma unroll
        for (int ni = 0; ni < 4; ++ni) {
            int r0 = brow + wrow + mi * 16 + quad * 4;
            int cc = bcol + wcol + ni * 16 + lane15;
#pragma unroll
            for (int r = 0; r < 4; ++r) {
                float v = acc[mi][ni][r];
                if constexpr (sizeof(CT) == 2) C[(long)(r0 + r) * ldc + cc] = f2bf(v);
                else                           C[(long)(r0 + r) * ldc + cc] = v;
            }
        }
    }
}

// ---------------------------------------------------------------------------
// Fused flash attention, v2 (transposed-S + register prefetch).
// grid (SEQ/128, NH), 256 thr = 4 waves; wave w owns q rows [bq*128+w*32, +32).
// Per 64-key tile: S^T = mfma(K,Q) (C-layout col=q) -> in-lane softmax reduce
// (+2 shfl_xor) -> P packed to wave-private LDS as [q][key] via ushort4 ->
// O^T += mfma(V^T, P). K/V tile t+1 global loads issued at top of iter t,
// ds_written after the end barrier (latency hidden behind compute).
// LDS pitches 200/72: row stride ≡ 4 banks -> 2-way aliasing only (free).
// ---------------------------------------------------------------------------
__global__ __launch_bounds__(256, 2) void flash_attn(
    const u16* __restrict__ qb, const u16* __restrict__ kb,
    const u16* __restrict__ vT, u16* __restrict__ ob, float scale)
{
    __shared__ u16 Ks[64 * 200];      // 25.6 KB
    __shared__ u16 Vs[128 * 72];      // 18.4 KB
    __shared__ u16 Ps[4 * 32 * 72];   // 18.4 KB, wave-private [32 q][72]

    const int t = threadIdx.x;
    const int w = t >> 6, lane = t & 63;
    const int lane15 = lane & 15, quad = lane >> 4;
    const int h = blockIdx.y;
    const int q0 = blockIdx.x * 128 + w * 32;
    u16* Psw = Ps + w * 32 * 72;

    // Q fragments (B-operand): Q[q = qt*16+lane15][d = kc*32+quad*8 ..]
    bf16x8 Qf[2][6];
#pragma unroll
    for (int qt = 0; qt < 2; ++qt)
#pragma unroll
        for (int kc = 0; kc < 6; ++kc)
            Qf[qt][kc] = *(const bf16x8*)(
                qb + (long)(h * SEQ + q0 + qt * 16 + lane15) * 192 + kc * 32 + quad * 8);

    // O^T accumulators: O[dt][qt], C-layout row=d(quad*4+r), col=q(lane15)
    f32x4 O[8][2] = {};
    float mst[2] = { -3.0e38f, -3.0e38f }, lst[2] = { 0.f, 0.f };

    // staging lambdas -----------------------------------------------------
    bf16x8 Kpf[6], Vpf[4];
    auto load_tiles = [&](int kt) {
#pragma unroll
        for (int i = 0; i < 6; ++i) {
            int chunk = i * 256 + t;          // 1536 chunks of 8
            int row = chunk / 24, c8 = (chunk % 24) * 8;
            Kpf[i] = *(const bf16x8*)(kb + (long)(h * SEQ + kt * 64 + row) * 192 + c8);
        }
#pragma unroll
        for (int i = 0; i < 4; ++i) {
            int chunk = i * 256 + t;          // 1024 chunks of 8
            int dh = chunk >> 3, c8 = (chunk & 7) * 8;
            Vpf[i] = *(const bf16x8*)(vT + (long)(h * 128 + dh) * SEQ + kt * 64 + c8);
        }
    };
    auto store_tiles = [&]() {
#pragma unroll
        for (int i = 0; i < 6; ++i) {
            int chunk = i * 256 + t;
            int row = chunk / 24, c8 = (chunk % 24) * 8;
            *(bf16x8*)(Ks + row * 200 + c8) = Kpf[i];
        }
#pragma unroll
        for (int i = 0; i < 4; ++i) {
            int chunk = i * 256 + t;
            int dh = chunk >> 3, c8 = (chunk & 7) * 8;
            *(bf16x8*)(Vs + dh * 72 + c8) = Vpf[i];
        }
    };

    load_tiles(0);
    store_tiles();
    __syncthreads();

    for (int kt = 0; kt < SEQ / 64; ++kt) {
        // prefetch next tile into regs (clamped on last iter; no wait here)
        load_tiles(kt + 1 < SEQ / 64 ? kt + 1 : kt);

        // ---- S^T = K @ Q^T : St[kt4][qt], row=key(quad*4+r), col=q(lane15) ----
        f32x4 St[4][2] = {};
#pragma unroll
        for (int kc = 0; kc < 6; ++kc) {
            bf16x8 Kf[4];
#pragma unroll
            for (int k4 = 0; k4 < 4; ++k4)
                Kf[k4] = *(const bf16x8*)(Ks + (k4 * 16 + lane15) * 200 + kc * 32 + quad * 8);
#pragma unroll
            for (int k4 = 0; k4 < 4; ++k4)
#pragma unroll
                for (int qt = 0; qt < 2; ++qt)
                    St[k4][qt] = __builtin_amdgcn_mfma_f32_16x16x32_bf16(
                        Kf[k4], Qf[qt][kc], St[k4][qt], 0, 0, 0);
        }

        // ---- online softmax per q-column (in-lane over 16 keys + 2 shfl) ----
#pragma unroll
        for (int qt = 0; qt < 2; ++qt) {
            float rm = St[0][qt][0];
#pragma unroll
            for (int k4 = 0; k4 < 4; ++k4)
#pragma unroll
                for (int r = 0; r < 4; ++r) rm = fmaxf(rm, St[k4][qt][r]);
            rm = fmaxf(rm, __shfl_xor(rm, 16, 64));
            rm = fmaxf(rm, __shfl_xor(rm, 32, 64));
            rm *= scale;
            float mnew = fmaxf(mst[qt], rm);
            float alpha = __expf(mst[qt] - mnew);
            mst[qt] = mnew;
            float rs = 0.f;
#pragma unroll
            for (int k4 = 0; k4 < 4; ++k4)
#pragma unroll
                for (int r = 0; r < 4; ++r) {
                    float pv = __expf(St[k4][qt][r] * scale - mnew);
                    St[k4][qt][r] = pv; rs += pv;
                }
            rs += __shfl_xor(rs, 16, 64);
            rs += __shfl_xor(rs, 32, 64);
            lst[qt] = lst[qt] * alpha + rs;
#pragma unroll
            for (int dt = 0; dt < 8; ++dt)
#pragma unroll
                for (int r = 0; r < 4; ++r) O[dt][qt][r] *= alpha;
        }

        // ---- P -> wave-private LDS as [q][key] (4 consecutive keys packed) ----
#pragma unroll
        for (int qt = 0; qt < 2; ++qt)
#pragma unroll
            for (int k4 = 0; k4 < 4; ++k4) {
                ushort4 pk;
                pk.x = f2bf(St[k4][qt][0]); pk.y = f2bf(St[k4][qt][1]);
                pk.z = f2bf(St[k4][qt][2]); pk.w = f2bf(St[k4][qt][3]);
                *(ushort4*)(Psw + (qt * 16 + lane15) * 72 + k4 * 16 + quad * 4) = pk;
            }

        // ---- O^T += V^T @ P^T : mfma(Vf (m=d), Pf (n=q)) ----
#pragma unroll
        for (int kc2 = 0; kc2 < 2; ++kc2) {
            bf16x8 Pf[2], Vf[8];
#pragma unroll
            for (int qt = 0; qt < 2; ++qt)
                Pf[qt] = *(const bf16x8*)(Psw + (qt * 16 + lane15) * 72 + kc2 * 32 + quad * 8);
#pragma unroll
            for (int dt = 0; dt < 8; ++dt)
                Vf[dt] = *(const bf16x8*)(Vs + (dt * 16 + lane15) * 72 + kc2 * 32 + quad * 8);
#pragma unroll
            for (int dt = 0; dt < 8; ++dt)
#pragma unroll
                for (int qt = 0; qt < 2; ++qt)
                    O[dt][qt] = __builtin_amdgcn_mfma_f32_16x16x32_bf16(
                        Vf[dt], Pf[qt], O[dt][qt], 0, 0, 0);
        }
        __syncthreads();          // all waves done reading Ks/Vs
        store_tiles();            // write tile kt+1 (waits vmcnt on prefetch)
        __syncthreads();          // staging visible
    }

    // ---- epilogue: O^T cols are q, rows are d; pack 4 d per store ----
#pragma unroll
    for (int qt = 0; qt < 2; ++qt) {
        float inv = 1.f / lst[qt];
        int s = q0 + qt * 16 + lane15;
#pragma unroll
        for (int dt = 0; dt < 8; ++dt) {
            ushort4 ov;
            ov.x = f2bf(O[dt][qt][0] * inv); ov.y = f2bf(O[dt][qt][1] * inv);
            ov.z = f2bf(O[dt][qt][2] * inv); ov.w = f2bf(O[dt][qt][3] * inv);
            *(ushort4*)(ob + (long)s * 4096 + h * 128 + dt * 16 + quad * 4) = ov;
        }
    }
}

// ---------------------------------------------------------------------------
__global__ void cast_bf16_k(const float* __restrict__ in, u16* __restrict__ out, long n)
{
    long i = ((long)blockIdx.x * 256 + threadIdx.x) * 4;
    if (i >= n) return;
    float4 v = *(const float4*)(in + i);
    ushort4 o;
    o.x = f2bf(v.x); o.y = f2bf(v.y); o.z = f2bf(v.z); o.w = f2bf(v.w);
    *(ushort4*)(out + i) = o;
}

__global__ void transpose_cast(const float* __restrict__ in, u16* __restrict__ out,
                               int K, int N, int Npad)
{
    __shared__ float tile[32][33];
    int n0 = blockIdx.x * 32, k0 = blockIdx.y * 32;
    int tx = threadIdx.x, ty = threadIdx.y;
#pragma unroll
    for (int i = 0; i < 32; i += 8) {
        int k = k0 + ty + i, n = n0 + tx;
        tile[ty + i][tx] = (n < N) ? in[(long)k * N + n] : 0.f;
    }
    __syncthreads();
#pragma unroll
    for (int i = 0; i < 32; i += 8) {
        int n = n0 + ty + i, k = k0 + tx;
        out[(long)n * K + k] = f2bf(tile[tx][ty + i]);
    }
}

__global__ __launch_bounds__(256) void rmsnorm_k(
    const u16* __restrict__ in, const float* __restrict__ g,
    u16* __restrict__ out, int C, int ldin)
{
    const int row = blockIdx.x;
    const u16* x = in + (long)row * ldin;
    float ss = 0.f;
    for (int c = threadIdx.x; c < C; c += 256) { float v = bf2f(x[c]); ss += v * v; }
#pragma unroll
    for (int off = 32; off; off >>= 1) ss += __shfl_down(ss, off, 64);
    __shared__ float red[4];
    if ((threadIdx.x & 63) == 0) red[threadIdx.x >> 6] = ss;
    __syncthreads();
    float tot = red[0] + red[1] + red[2] + red[3];
    float r = rsqrtf(tot / (float)C + 1.1920929e-07f);
    for (int c = threadIdx.x; c < C; c += 256)
        out[(long)row * C + c] = f2bf(bf2f(x[c]) * r * g[c]);
}

// ---------------------------------------------------------------------------
// RoPE tables: ct/st[s][j] = cos/sin(s * 10000^(-2j/64)), j<32
// ---------------------------------------------------------------------------
__global__ void rope_tab_k(float* __restrict__ ct, float* __restrict__ st)
{
    int idx = blockIdx.x * 256 + threadIdx.x;   // SEQ*32 total
    int s = idx >> 5, j = idx & 31;
    float invf = powf(10000.f, -(float)(2 * j) / 64.f);
    float fr = (float)s * invf;
    float sn, cs; sincosf(fr, &sn, &cs);
    ct[idx] = cs; st[idx] = sn;
}

__device__ __forceinline__ float rope_val(const u16* src, int i, int s,
                                          const float* ct, const float* st)
{
    int j = i & 31;
    float cs = ct[s * 32 + j], sn = st[s * 32 + j];
    float x = bf2f(src[i]);
    float xo = (i < 32) ? bf2f(src[i + 32]) : bf2f(src[i - 32]);
    return (i < 32) ? (x * cs - xo * sn) : (x * cs + xo * sn);
}

// q[NH][SEQ][192] from qcr[SEQ][NH*192] (rope on last 64). grid (SEQ,NH) block 192
__global__ void build_q_k(const u16* __restrict__ qcr, u16* __restrict__ q,
                          const float* __restrict__ ct, const float* __restrict__ st)
{
    int s = blockIdx.x, h = blockIdx.y, d = threadIdx.x;
    const u16* src = qcr + ((long)s * NH + h) * 192;
    float val = (d < 128) ? bf2f(src[d]) : rope_val(src + 128, d - 128, s, ct, st);
    q[((long)h * SEQ + s) * 192 + d] = f2bf(val);
}

__global__ void build_k_k(const u16* __restrict__ kv, const u16* __restrict__ ropebuf,
                          int ldrope, u16* __restrict__ kbuf,
                          const float* __restrict__ ct, const float* __restrict__ st)
{
    int s = blockIdx.x, h = blockIdx.y, d = threadIdx.x;
    float val = (d < 128) ? bf2f(kv[(long)s * 8192 + h * 256 + d])
                          : rope_val(ropebuf + (long)s * ldrope, d - 128, s, ct, st);
    kbuf[((long)h * SEQ + s) * 192 + d] = f2bf(val);
}

// vT[NH][128][SEQ] from kv[SEQ][8192] (v = cols h*256+128 .. +255)
__global__ void build_vT_k(const u16* __restrict__ kv, u16* __restrict__ vT)
{
    __shared__ u16 tile[32][33];
    int s0 = blockIdx.x * 32, d0 = blockIdx.y * 32, h = blockIdx.z;
    int tx = threadIdx.x, ty = threadIdx.y;
#pragma unroll
    for (int i = 0; i < 32; i += 8)
        tile[ty + i][tx] = kv[(long)(s0 + ty + i) * 8192 + h * 256 + 128 + d0 + tx];
    __syncthreads();
#pragma unroll
    for (int i = 0; i < 32; i += 8)
        vT[((long)h * 128 + d0 + ty + i) * SEQ + s0 + tx] = tile[tx][ty + i];
}

// ---------------------------------------------------------------------------
extern "C" void kernel_launch(void* const* d_in, const int* in_sizes, int n_in,
                              void* d_out, int out_size, void* d_ws, size_t ws_size,
                              hipStream_t stream)
{
    const float* hidden = (const float*)d_in[0];
    const float* W_dq   = (const float*)d_in[1];
    const float* g_q    = (const float*)d_in[2];
    const float* W_uq   = (const float*)d_in[3];
    const float* W_dkv  = (const float*)d_in[4];
    const float* g_kv   = (const float*)d_in[5];
    const float* W_ukv  = (const float*)d_in[6];
    const float* W_o    = (const float*)d_in[7];
    float* out = (float*)d_out;

    char* p = (char*)d_ws;
    auto alloc = [&](size_t bytes) {
        char* r = p; p += (bytes + 255) & ~(size_t)255; return r;
    };
    u16* hbf   = (u16*)alloc((size_t)SEQ * HIDDEN * 2);
    u16* WTqkv = (u16*)alloc((size_t)NQKV * HIDDEN * 2);
    u16* WTuq  = (u16*)alloc((size_t)6144 * DQ * 2);
    u16* WTukv = (u16*)alloc((size_t)8192 * DKV * 2);
    u16* WTo   = (u16*)alloc((size_t)HIDDEN * 4096 * 2);
    u16* cqc   = (u16*)alloc((size_t)SEQ * NQKV * 2);
    u16* nq    = (u16*)alloc((size_t)SEQ * DQ * 2);
    u16* qcr   = (u16*)alloc((size_t)SEQ * 6144 * 2);
    u16* nkv   = (u16*)alloc((size_t)SEQ * DKV * 2);
    u16* kvb   = (u16*)alloc((size_t)SEQ * 8192 * 2);
    u16* qb    = (u16*)alloc((size_t)NH * SEQ * 192 * 2);
    u16* kb    = (u16*)alloc((size_t)NH * SEQ * 192 * 2);
    u16* vT    = (u16*)alloc((size_t)NH * 128 * SEQ * 2);
    u16* ob    = (u16*)alloc((size_t)SEQ * 4096 * 2);
    float* ct  = (float*)alloc((size_t)SEQ * 32 * 4);
    float* st  = (float*)alloc((size_t)SEQ * 32 * 4);
    (void)in_sizes; (void)n_in; (void)out_size; (void)ws_size;

    // --- prep: rope tables, casts, weight transposes ---
    rope_tab_k<<<(SEQ * 32) / 256, 256, 0, stream>>>(ct, st);
    cast_bf16_k<<<((long)SEQ * HIDDEN) / 1024, 256, 0, stream>>>(hidden, hbf, (long)SEQ * HIDDEN);
    transpose_cast<<<dim3(DQ / 32, HIDDEN / 32), dim3(32, 8), 0, stream>>>(W_dq, WTqkv, HIDDEN, DQ, DQ);
    transpose_cast<<<dim3(DKVP / 32, HIDDEN / 32), dim3(32, 8), 0, stream>>>(
        W_dkv, WTqkv + (size_t)DQ * HIDDEN, HIDDEN, 576, DKVP);
    transpose_cast<<<dim3(6144 / 32, DQ / 32), dim3(32, 8), 0, stream>>>(W_uq, WTuq, DQ, 6144, 6144);
    transpose_cast<<<dim3(8192 / 32, DKV / 32), dim3(32, 8), 0, stream>>>(W_ukv, WTukv, DKV, 8192, 8192);
    transpose_cast<<<dim3(HIDDEN / 32, 4096 / 32), dim3(32, 8), 0, stream>>>(W_o, WTo, 4096, HIDDEN, HIDDEN);

    // --- fused down-projection: cqc = hbf @ [W_dq | W_dkv] ---
    gemm_bt<u16><<<dim3(NQKV / 128, SEQ / 128), 256, 0, stream>>>(
        hbf, WTqkv, cqc, HIDDEN, HIDDEN, HIDDEN, NQKV, 0, 0, 0);
    rmsnorm_k<<<SEQ, 256, 0, stream>>>(cqc, g_q, nq, DQ, NQKV);
    rmsnorm_k<<<SEQ, 256, 0, stream>>>(cqc + DQ, g_kv, nkv, DKV, NQKV);

    // --- up-projections ---
    gemm_bt<u16><<<dim3(6144 / 128, SEQ / 128), 256, 0, stream>>>(
        nq, WTuq, qcr, DQ, DQ, DQ, 6144, 0, 0, 0);
    gemm_bt<u16><<<dim3(8192 / 128, SEQ / 128), 256, 0, stream>>>(
        nkv, WTukv, kvb, DKV, DKV, DKV, 8192, 0, 0, 0);

    // --- assemble q/k (rope) and vT ---
    build_q_k<<<dim3(SEQ, NH), 192, 0, stream>>>(qcr, qb, ct, st);
    build_k_k<<<dim3(SEQ, NH), 192, 0, stream>>>(kvb, cqc + DQ + DKV, NQKV, kb, ct, st);
    build_vT_k<<<dim3(SEQ / 32, 4, NH), dim3(32, 8), 0, stream>>>(kvb, vT);

    // --- fused flash attention ---
    const float scale = 0.07216878364870322f;  // 1/sqrt(192)
    flash_attn<<<dim3(SEQ / 128, NH), 256, 0, stream>>>(qb, kb, vT, ob, scale);

    // --- output projection (fp32 out) ---
    gemm_bt<float><<<dim3(HIDDEN / 128, SEQ / 128), 256, 0, stream>>>(
        ob, WTo, out, 4096, 4096, 4096, HIDDEN, 0, 0, 0);
}